// Round 7
// baseline (194.747 us; speedup 1.0000x reference)
//
#include <hip/hip_runtime.h>
#include <math.h>

// PHM adapter: down (768->192, n=4 rank-1 kron) -> gelu_new -> up (192->768).
// Round 11: permlane swaps via BUILTINS (rounds 5/6 with inline-asm permlane
// died twice with opaque container failures; builtins produce identical code
// and fail loudly at compile time if unsupported).
// Rationale (round-4 analysis): rounds 0 and 9 hit the same 63-65us wall
// with different memory structures; per-CU accounting (VALU 19K + DS 53K +
// HBM 78K cyc ~= measured 156K) shows pipes running SERIALIZED. The shared
// serializer: 48 __shfl_xor per pair = ds_bpermute + lgkmcnt(0) round-trips
// mid-dependency-chain on a contended DS pipe. Fix: gfx950's
// v_permlane16/32_swap_b32 (VALU pipe). Three swaps broadcast all four
// row-sums H0..H3 to every lane with no select:
//   swap16(y1=h, y2=h): y1 = H[a&2], y2 = H[(a&2)|1]
//   swap32(b0=y1, b2=y1): b0 = H0 bcast, b2 = H2 bcast
//   swap32(b1=y2, b3=y2): b1 = H1 bcast, b3 = H3 bcast
// Rule contraction becomes sum_k b_k * rule[i][k][a]. DS ops/pair 116->68;
// all 48 mid-chain lgkm stalls gone. Everything else identical to round 9
// (coalesced per-lane remap p = a*192 + 4*(r+16u)+j, no LDS round-trip,
// 1-deep prefetch, nt stores, no min-wave hint -- (256,4) pins VGPR=64 and
// spills wholesale).

#define SQ2PI 0.79788456080286535588f

typedef float vfloat4 __attribute__((ext_vector_type(4)));
typedef unsigned int vuint2 __attribute__((ext_vector_type(2)));

template<int CTRL>
__device__ __forceinline__ float ror_add(float v) {
    // v + rotate_within_16(v, CTRL)  (DPP row_ror — VALU pipe, no DS traffic)
    int s = __builtin_amdgcn_update_dpp(0, __float_as_int(v), CTRL, 0xF, 0xF, true);
    return v + __int_as_float(s);
}
__device__ __forceinline__ float reduce16(float v) {
    v = ror_add<0x121>(v);   // row_ror:1
    v = ror_add<0x122>(v);   // row_ror:2
    v = ror_add<0x124>(v);   // row_ror:4
    v = ror_add<0x128>(v);   // row_ror:8
    return v;                // every lane: sum over its 16-lane row
}

// v_permlane16_swap_b32: exchanges odd 16-lane rows of d with even rows of s.
// v_permlane32_swap_b32: exchanges rows {2,3} of d with rows {0,1} of s.
// Builtins return the new (vdst, src) pair.
__device__ __forceinline__ void swap16(float& d, float& s) {
    vuint2 t = __builtin_amdgcn_permlane16_swap(__float_as_uint(d), __float_as_uint(s), false, false);
    d = __uint_as_float(t.x);  s = __uint_as_float(t.y);
}
__device__ __forceinline__ void swap32(float& d, float& s) {
    vuint2 t = __builtin_amdgcn_permlane32_swap(__float_as_uint(d), __float_as_uint(s), false, false);
    d = __uint_as_float(t.x);  s = __uint_as_float(t.y);
}
// After reduce16, all lanes of row a hold H_a. Broadcast all four H's to
// every lane in 3 swap instructions (VALU pipe), no cndmask needed.
__device__ __forceinline__ void bcast4(float h, float& b0, float& b1, float& b2, float& b3) {
    float y1 = h, y2 = h;
    swap16(y1, y2);                     // y1 = H[a&2], y2 = H[(a&2)|1]
    b0 = y1; b2 = y1; swap32(b0, b2);   // b0 = H0, b2 = H2 (broadcast)
    b1 = y2; b3 = y2; swap32(b1, b3);   // b1 = H1, b3 = H3 (broadcast)
}

__device__ __forceinline__ void nt_store4(float* p, const float4& v) {
    vfloat4 nv;
    nv.x = v.x; nv.y = v.y; nv.z = v.z; nv.w = v.w;
    __builtin_nontemporal_store(nv, (vfloat4*)p);
}

__global__ __launch_bounds__(256)
void phm_fused(const float* __restrict__ x,
               const float* __restrict__ rule_d,
               const float* __restrict__ Wl_d,
               const float* __restrict__ Wr_d,
               const float* __restrict__ bias_d,
               const float* __restrict__ rule_u,
               const float* __restrict__ Wl_u,
               const float* __restrict__ Wr_u,
               const float* __restrict__ bias_u,
               float* __restrict__ out,
               int n_tokens)
{
    __shared__ __attribute__((aligned(16))) float sLd[768];    // W_left_d  [i][p]  i*192+p
    __shared__ __attribute__((aligned(16))) float sRu[768];    // W_right_u [i][q2] i*192+q2
    __shared__ __attribute__((aligned(16))) float sLu[192];    // W_left_u  [i][q]  i*48+q
    __shared__ float sRuleD[64];                               // [i][a'][c] i*16+a'*4+c
    __shared__ float sRuleU[64];

    const int tid = threadIdx.x;
    for (int i = tid; i < 768; i += 256) sLd[i] = Wl_d[i];
    for (int i = tid; i < 768; i += 256) sRu[i] = Wr_u[i];
    if (tid < 192)      sLu[tid]        = Wl_u[tid];
    if (tid < 64)       sRuleD[tid]     = rule_d[tid];
    else if (tid < 128) sRuleU[tid-64]  = rule_u[tid-64];

    const int lane = tid & 63;
    const int wave = tid >> 6;
    const int a    = lane >> 4;          // kron block 0..3 (also dest c)
    const int r    = lane & 15;          // slot within block
    const int off  = 192*a + 4*r;        // coalesced remap: +64u walks the block

    // ---- small persistent registers (27 floats) ----
    float bd[3];                   // bias_d at o = a*48 + 3r + w   (gelu stage)
    float rdw[4][3];               // W_right_d[i][3r+w]
    float4 bu[3];                  // bias_u at q2-part 4r+64u of block a
    #pragma unroll
    for (int w = 0; w < 3; ++w) bd[w] = bias_d[a*48 + 3*r + w];
    #pragma unroll
    for (int i = 0; i < 4; ++i)
        #pragma unroll
        for (int w = 0; w < 3; ++w) rdw[i][w] = Wr_d[i*48 + 3*r + w];
    #pragma unroll
    for (int u = 0; u < 3; ++u)
        bu[u] = *(const float4*)(bias_u + off + 64*u);

    __syncthreads();   // the ONLY block barrier: weights staged

    const int wid     = blockIdx.x * 4 + wave;
    const int n_waves = gridDim.x * 4;
    const int n_pairs = n_tokens >> 1;

    // ---- prologue: load first pair (coalesced: 256B/row segments) ----
    float4 A0[3], A1[3];
    {
        const int pr0 = (wid < n_pairs) ? wid : 0;
        const float* xp = x + (size_t)pr0 * 1536 + off;
        #pragma unroll
        for (int u = 0; u < 3; ++u) {
            A0[u] = *(const float4*)(xp + 64*u);
            A1[u] = *(const float4*)(xp + 768 + 64*u);
        }
    }

    for (int pr = wid; pr < n_pairs; pr += n_waves) {
        // ---- prefetch next pair (clamped; last iter harmlessly reloads) ----
        const int nx = pr + n_waves;
        const float* np = x + (size_t)(nx < n_pairs ? nx : pr) * 1536 + off;
        float4 B0[3], B1[3];
        #pragma unroll
        for (int u = 0; u < 3; ++u) {
            B0[u] = *(const float4*)(np + 64*u);
            B1[u] = *(const float4*)(np + 768 + 64*u);
        }

        // ---- down dots: x[a*192 + 4r+64u + j] * Wl_d[i][4r+64u + j] ----
        float s0[4] = {0,0,0,0}, s1[4] = {0,0,0,0};
        #pragma unroll
        for (int u = 0; u < 3; ++u) {
            const float4 xa = A0[u];
            const float4 xb = A1[u];
            #pragma unroll
            for (int i = 0; i < 4; ++i) {
                const float4 lv = *(const float4*)&sLd[i*192 + 4*r + 64*u];
                s0[i] = fmaf(xa.x, lv.x, s0[i]);  s1[i] = fmaf(xb.x, lv.x, s1[i]);
                s0[i] = fmaf(xa.y, lv.y, s0[i]);  s1[i] = fmaf(xb.y, lv.y, s1[i]);
                s0[i] = fmaf(xa.z, lv.z, s0[i]);  s1[i] = fmaf(xb.z, lv.z, s1[i]);
                s0[i] = fmaf(xa.w, lv.w, s0[i]);  s1[i] = fmaf(xb.w, lv.w, s1[i]);
            }
        }

        // ---- 16-lane DPP reduce + permlane broadcast + rule contraction ----
        float tD0[4], tD1[4];
        #pragma unroll
        for (int i = 0; i < 4; ++i) {
            const float rk0 = sRuleD[i*16 +  0 + a];   // rule[i][0][a]
            const float rk1 = sRuleD[i*16 +  4 + a];   // rule[i][1][a]
            const float rk2 = sRuleD[i*16 +  8 + a];   // rule[i][2][a]
            const float rk3 = sRuleD[i*16 + 12 + a];   // rule[i][3][a]
            float b0, b1, b2, b3;
            bcast4(reduce16(s0[i]), b0, b1, b2, b3);
            tD0[i] = fmaf(b0, rk0, fmaf(b1, rk1, fmaf(b2, rk2, b3 * rk3)));
            bcast4(reduce16(s1[i]), b0, b1, b2, b3);
            tD1[i] = fmaf(b0, rk0, fmaf(b1, rk1, fmaf(b2, rk2, b3 * rk3)));
        }

        // ---- z + gelu at o = a*48 + 3r + w (mapping unchanged) ----
        float g0[3], g1[3];
        #pragma unroll
        for (int w = 0; w < 3; ++w) {
            float z0 = bd[w], z1 = bd[w];
            #pragma unroll
            for (int i = 0; i < 4; ++i) {
                z0 = fmaf(tD0[i], rdw[i][w], z0);
                z1 = fmaf(tD1[i], rdw[i][w], z1);
            }
            const float i0 = SQ2PI * fmaf(0.044715f*z0, z0*z0, z0);
            const float i1 = SQ2PI * fmaf(0.044715f*z1, z1*z1, z1);
            const float e0 = __expf(2.0f*i0);                // tanh(y)=1-2/(e^{2y}+1)
            const float e1 = __expf(2.0f*i1);
            g0[w] = 0.5f*z0*(1.0f + (1.0f - 2.0f/(e0 + 1.0f)));
            g1[w] = 0.5f*z1*(1.0f + (1.0f - 2.0f/(e1 + 1.0f)));
        }

        // ---- up dots + reduce + broadcast + rule contraction ----
        float tU0[4], tU1[4];
        #pragma unroll
        for (int i = 0; i < 4; ++i) {
            const float l0 = sLu[i*48 + 3*r + 0];
            const float l1 = sLu[i*48 + 3*r + 1];
            const float l2 = sLu[i*48 + 3*r + 2];
            const float rk0 = sRuleU[i*16 +  0 + a];
            const float rk1 = sRuleU[i*16 +  4 + a];
            const float rk2 = sRuleU[i*16 +  8 + a];
            const float rk3 = sRuleU[i*16 + 12 + a];
            float a0 = g0[0]*l0 + g0[1]*l1 + g0[2]*l2;
            float a1 = g1[0]*l0 + g1[1]*l1 + g1[2]*l2;
            float b0, b1, b2, b3;
            bcast4(reduce16(a0), b0, b1, b2, b3);
            tU0[i] = fmaf(b0, rk0, fmaf(b1, rk1, fmaf(b2, rk2, b3 * rk3)));
            bcast4(reduce16(a1), b0, b1, b2, b3);
            tU1[i] = fmaf(b0, rk0, fmaf(b1, rk1, fmaf(b2, rk2, b3 * rk3)));
        }

        // ---- outputs: coalesced nt stores (tU is row-broadcast, so lane
        //      writes the q2-slice 4r+64u of its block -> 256B/row segments)
        float* op = out + (size_t)pr * 1536 + off;
        #pragma unroll
        for (int u = 0; u < 3; ++u) {
            float4 ov0 = bu[u], ov1 = bu[u];
            #pragma unroll
            for (int i = 0; i < 4; ++i) {
                const float4 ru = *(const float4*)&sRu[i*192 + 4*r + 64*u];
                ov0.x = fmaf(tU0[i], ru.x, ov0.x);  ov1.x = fmaf(tU1[i], ru.x, ov1.x);
                ov0.y = fmaf(tU0[i], ru.y, ov0.y);  ov1.y = fmaf(tU1[i], ru.y, ov1.y);
                ov0.z = fmaf(tU0[i], ru.z, ov0.z);  ov1.z = fmaf(tU1[i], ru.z, ov1.z);
                ov0.w = fmaf(tU0[i], ru.w, ov0.w);  ov1.w = fmaf(tU1[i], ru.w, ov1.w);
            }
            nt_store4(op + 64*u,       ov0);
            nt_store4(op + 768 + 64*u, ov1);
        }

        // ---- rotate prefetch into current ----
        #pragma unroll
        for (int u = 0; u < 3; ++u) { A0[u] = B0[u]; A1[u] = B1[u]; }
    }
}

extern "C" void kernel_launch(void* const* d_in, const int* in_sizes, int n_in,
                              void* d_out, int out_size, void* d_ws, size_t ws_size,
                              hipStream_t stream) {
    const float* x      = (const float*)d_in[0];
    const float* rule_d = (const float*)d_in[1];
    const float* Wl_d   = (const float*)d_in[2];
    const float* Wr_d   = (const float*)d_in[3];
    const float* bias_d = (const float*)d_in[4];
    const float* rule_u = (const float*)d_in[5];
    const float* Wl_u   = (const float*)d_in[6];
    const float* Wr_u   = (const float*)d_in[7];
    const float* bias_u = (const float*)d_in[8];
    float* out          = (float*)d_out;

    const int n_tokens = in_sizes[0] / 768;   // 32768

    // 1024 blocks = 4096 waves; 16384 pairs -> exactly 4 pairs/wave, balanced.
    phm_fused<<<dim3(1024), dim3(256), 0, stream>>>(
        x, rule_d, Wl_d, Wr_d, bias_d, rule_u, Wl_u, Wr_u, bias_u, out, n_tokens);
}